// Round 7
// baseline (174.270 us; speedup 1.0000x reference)
//
#include <hip/hip_runtime.h>
#include <math.h>

// ---------------------------------------------------------------------------
// DMoN pooling, edge-list formulation (dense adj never materialized).
//   0. setup: zero deg/cnt/cur/ctr ; x->bf16 ; W1,W2 -> transposed bf16 hi/lo
//   1. CSR-by-dst build (count / scan / scatter-with-inline-rsqrt)
//   2. layer 1: (axhi,axlo) = split(aggregate(x_bf))   [bf16 gather, fp32 acc]
//               h_bf = bf16(relu(ax@W1 + b1))          [3-term MFMA GEMM]
//   3. layer 2: (ahhi,ahlo) = split(aggregate(h_bf)) ; h2 = relu(ah@W2+b2)
//   4. s = softmax(h2@Wp + bp) -> d_out ; per-block cluster-size partials
//   5. per-edge reduction -> per-block partials ; last block finalizes
// ---------------------------------------------------------------------------

#define ER_BLOCKS 128

typedef unsigned short u16;
typedef __attribute__((ext_vector_type(8))) short short8v;
typedef __attribute__((ext_vector_type(4))) float float4v;
typedef __attribute__((ext_vector_type(4))) unsigned short ushort4v;

__device__ __forceinline__ u16 f2bf_rne(float x) {
  unsigned u = __float_as_uint(x);
  u = (u + 0x7fffu + ((u >> 16) & 1u)) >> 16;
  return (u16)u;
}
__device__ __forceinline__ float bf2f(u16 h) {
  return __uint_as_float(((unsigned)h) << 16);
}

// edge_index declared int64 in the reference, but JAX without x64 keeps int32.
__device__ __forceinline__ bool ei_is_i64(const int* __restrict__ ei) {
  return ((ei[1] | ei[3] | ei[5] | ei[7]) == 0);
}
__device__ __forceinline__ int ld_idx(const int* __restrict__ ei, int pos, bool i64) {
  return i64 ? ei[2 * pos] : ei[pos];
}

// Fused setup: zero scratch region, convert x->bf16, W1/W2 -> [n][k] bf16 hi/lo.
__global__ __launch_bounds__(256) void setup_kernel(int4* __restrict__ zp, int zn4,
                                                    const float* __restrict__ x,
                                                    u16* __restrict__ xbf, int nx4,
                                                    const float* __restrict__ W1,
                                                    u16* __restrict__ w1hi, u16* __restrict__ w1lo,
                                                    const float* __restrict__ W2,
                                                    u16* __restrict__ w2hi, u16* __restrict__ w2lo) {
  const int T1 = 256 * 128, T2 = 256 * 256;
  int idx = blockIdx.x * 256 + threadIdx.x;
  if (idx < zn4) {
    zp[idx] = make_int4(0, 0, 0, 0);
    return;
  }
  idx -= zn4;
  if (idx < nx4) {  // x -> bf16, 4 at a time
    float4 v = reinterpret_cast<const float4*>(x)[idx];
    ushort4v o = {f2bf_rne(v.x), f2bf_rne(v.y), f2bf_rne(v.z), f2bf_rne(v.w)};
    reinterpret_cast<ushort4v*>(xbf)[idx] = o;
    return;
  }
  idx -= nx4;
  if (idx < T1) {  // W1t
    int n = idx >> 7, k = idx & 127;
    float v = W1[k * 256 + n];
    u16 h = f2bf_rne(v);
    w1hi[idx] = h;
    w1lo[idx] = f2bf_rne(v - bf2f(h));
    return;
  }
  idx -= T1;
  if (idx < T2) {  // W2t
    int n = idx >> 8, k = idx & 255;
    float v = W2[k * 256 + n];
    u16 h = f2bf_rne(v);
    w2hi[idx] = h;
    w2lo[idx] = f2bf_rne(v - bf2f(h));
  }
}

__global__ __launch_bounds__(256) void edge_count(const int* __restrict__ ei,
                                                  const float* __restrict__ ew,
                                                  int* __restrict__ cnt,
                                                  float* __restrict__ deg, int E) {
  int e = blockIdx.x * 256 + threadIdx.x;
  if (e >= E) return;
  bool i64 = ei_is_i64(ei);
  int d = ld_idx(ei, E + e, i64);
  atomicAdd(&cnt[d], 1);
  atomicAdd(&deg[d], ew[e]);
}

__global__ __launch_bounds__(1024) void scan_kernel(const int* __restrict__ cnt,
                                                    int* __restrict__ rowptr, int n) {
  __shared__ int sums[1024];
  int tid = threadIdx.x;
  int CH = (n + 1023) >> 10;
  int beg = tid * CH, end = min(beg + CH, n);
  int s = 0;
  for (int i = beg; i < end; ++i) s += cnt[i];
  sums[tid] = s;
  __syncthreads();
  for (int off = 1; off < 1024; off <<= 1) {
    int v = (tid >= off) ? sums[tid - off] : 0;
    __syncthreads();
    sums[tid] += v;
    __syncthreads();
  }
  int run = (tid == 0) ? 0 : sums[tid - 1];
  for (int i = beg; i < end; ++i) { rowptr[i] = run; run += cnt[i]; }
  if (tid == 1023) rowptr[n] = run;
}

__global__ __launch_bounds__(256) void scatter_edges(const int* __restrict__ ei,
                                                     const float* __restrict__ ew,
                                                     const int* __restrict__ rowptr,
                                                     int* __restrict__ cur,
                                                     const float* __restrict__ deg,
                                                     int* __restrict__ col,
                                                     float* __restrict__ coef, int E) {
  int e = blockIdx.x * 256 + threadIdx.x;
  if (e >= E) return;
  bool i64 = ei_is_i64(ei);
  int s = ld_idx(ei, e, i64);
  int d = ld_idx(ei, E + e, i64);
  int p = rowptr[d] + atomicAdd(&cur[d], 1);
  col[p] = s;
  float ds = 1.0f / sqrtf(deg[s] + 1.0f);
  float dd = 1.0f / sqrtf(deg[d] + 1.0f);
  coef[p] = ds * ew[e] * dd;
}

// Normalized aggregation: bf16 gather operand, fp32 accumulate, hi/lo output.
template <int CH>
__global__ __launch_bounds__(256) void aggregate_pre(const u16* __restrict__ src,
                                                     const int* __restrict__ rowptr,
                                                     const int* __restrict__ col,
                                                     const float* __restrict__ coef,
                                                     const float* __restrict__ deg,
                                                     u16* __restrict__ ohi,
                                                     u16* __restrict__ olo, int N) {
  constexpr int Q = CH / 4;
  constexpr int NS = 256 / Q;
  int i = blockIdx.x;
  int t = threadIdx.x;
  int q = t % Q, slot = t / Q;
  int e0 = rowptr[i], e1 = rowptr[i + 1];
  float4 acc = make_float4(0.f, 0.f, 0.f, 0.f);
  for (int p = e0 + slot; p < e1; p += NS) {
    int c = col[p];
    float w = coef[p];
    ushort4v v = *reinterpret_cast<const ushort4v*>(&src[(size_t)c * CH + q * 4]);
    acc.x += w * bf2f(v[0]); acc.y += w * bf2f(v[1]);
    acc.z += w * bf2f(v[2]); acc.w += w * bf2f(v[3]);
  }
  __shared__ float4 red[256];
  red[t] = acc;
  __syncthreads();
  if (slot == 0) {
#pragma unroll
    for (int s2 = 1; s2 < NS; ++s2) {
      float4 o = red[s2 * Q + q];
      acc.x += o.x; acc.y += o.y; acc.z += o.z; acc.w += o.w;
    }
    float w0 = 1.0f / (deg[i] + 1.0f);
    ushort4v xv = *reinterpret_cast<const ushort4v*>(&src[(size_t)i * CH + q * 4]);
    acc.x += w0 * bf2f(xv[0]); acc.y += w0 * bf2f(xv[1]);
    acc.z += w0 * bf2f(xv[2]); acc.w += w0 * bf2f(xv[3]);
    float a[4] = {acc.x, acc.y, acc.z, acc.w};
    ushort4v hv, lv;
#pragma unroll
    for (int j = 0; j < 4; ++j) {
      u16 h = f2bf_rne(a[j]);
      hv[j] = h;
      lv[j] = f2bf_rne(a[j] - bf2f(h));
    }
    *reinterpret_cast<ushort4v*>(&ohi[(size_t)i * CH + q * 4]) = hv;
    *reinterpret_cast<ushort4v*>(&olo[(size_t)i * CH + q * 4]) = lv;
  }
}

// C[M,256] = relu(A@B + bias) via 3-term bf16 MFMA (A=Ahi+Alo, B=Bhi+Blo).
// Output: fp32 C (if Cbf==nullptr-like flag outbf=0) or bf16 Cbf (outbf=1).
__global__ __launch_bounds__(256) void gemm_mfma(const u16* __restrict__ Ahi,
                                                 const u16* __restrict__ Alo,
                                                 const u16* __restrict__ Wthi,
                                                 const u16* __restrict__ Wtlo,
                                                 const float* __restrict__ bias,
                                                 float* __restrict__ C,
                                                 u16* __restrict__ Cbf,
                                                 int M, int K, int outbf) {
  __shared__ u16 As_hi[64][40], As_lo[64][40];  // [m][k], pad 32->40
  __shared__ u16 Bs_hi[64][40], Bs_lo[64][40];  // [n][k]
  int tid = threadIdx.x;
  int w = tid >> 6, l = tid & 63;
  int wm = w >> 1, wn = w & 1;
  int row0 = blockIdx.x * 64, col0 = blockIdx.y * 64;
  int srow = tid >> 2, sc = (tid & 3) * 8;
  int fr = l & 15, kg = (l >> 4) * 8;

  float4v acc[2][2];
#pragma unroll
  for (int i = 0; i < 2; ++i)
#pragma unroll
    for (int j = 0; j < 2; ++j) acc[i][j] = (float4v){0.f, 0.f, 0.f, 0.f};

  for (int k0 = 0; k0 < K; k0 += 32) {
    {
      int gr = row0 + srow;
      uint4 zero = make_uint4(0, 0, 0, 0);
      uint4 vh = zero, vl = zero;
      if (gr < M) {
        vh = *reinterpret_cast<const uint4*>(&Ahi[(size_t)gr * K + k0 + sc]);
        vl = *reinterpret_cast<const uint4*>(&Alo[(size_t)gr * K + k0 + sc]);
      }
      *reinterpret_cast<uint4*>(&As_hi[srow][sc]) = vh;
      *reinterpret_cast<uint4*>(&As_lo[srow][sc]) = vl;
      int bn = col0 + srow;
      uint4 bh = *reinterpret_cast<const uint4*>(&Wthi[(size_t)bn * K + k0 + sc]);
      uint4 bl = *reinterpret_cast<const uint4*>(&Wtlo[(size_t)bn * K + k0 + sc]);
      *reinterpret_cast<uint4*>(&Bs_hi[srow][sc]) = bh;
      *reinterpret_cast<uint4*>(&Bs_lo[srow][sc]) = bl;
    }
    __syncthreads();
    short8v ah[2], al[2], bh[2], bl[2];
#pragma unroll
    for (int i = 0; i < 2; ++i) {
      int r = wm * 32 + i * 16 + fr;
      ah[i] = *reinterpret_cast<const short8v*>(&As_hi[r][kg]);
      al[i] = *reinterpret_cast<const short8v*>(&As_lo[r][kg]);
    }
#pragma unroll
    for (int j = 0; j < 2; ++j) {
      int n = wn * 32 + j * 16 + fr;
      bh[j] = *reinterpret_cast<const short8v*>(&Bs_hi[n][kg]);
      bl[j] = *reinterpret_cast<const short8v*>(&Bs_lo[n][kg]);
    }
#pragma unroll
    for (int i = 0; i < 2; ++i)
#pragma unroll
      for (int j = 0; j < 2; ++j) {
        acc[i][j] = __builtin_amdgcn_mfma_f32_16x16x32_bf16(ah[i], bh[j], acc[i][j], 0, 0, 0);
        acc[i][j] = __builtin_amdgcn_mfma_f32_16x16x32_bf16(al[i], bh[j], acc[i][j], 0, 0, 0);
        acc[i][j] = __builtin_amdgcn_mfma_f32_16x16x32_bf16(ah[i], bl[j], acc[i][j], 0, 0, 0);
      }
    __syncthreads();
  }
  // epilogue: C/D col = lane&15, row = (lane>>4)*4 + reg
#pragma unroll
  for (int j = 0; j < 2; ++j) {
    int gc = col0 + wn * 32 + j * 16 + fr;
    float bj = bias[gc];
#pragma unroll
    for (int i = 0; i < 2; ++i) {
#pragma unroll
      for (int r = 0; r < 4; ++r) {
        int gr = row0 + wm * 32 + i * 16 + (l >> 4) * 4 + r;
        if (gr < M) {
          float v = fmaxf(acc[i][j][r] + bj, 0.0f);
          if (outbf) Cbf[(size_t)gr * 256 + gc] = f2bf_rne(v);
          else       C[(size_t)gr * 256 + gc] = v;
        }
      }
    }
  }
}

// Pooling + softmax + per-block cluster-size partials.
__global__ __launch_bounds__(256) void pool_kernel(const float* __restrict__ h,
                                                   const float* __restrict__ Wp,
                                                   const float* __restrict__ bp,
                                                   float* __restrict__ s_out,
                                                   float* __restrict__ cs_part, int N) {
  __shared__ float Wps[256 * 16];
  __shared__ float cs_loc[16];
  int tid = threadIdx.x;
  for (int idx = tid; idx < 4096; idx += 256) Wps[idx] = Wp[idx];
  if (tid < 16) cs_loc[tid] = 0.f;
  __syncthreads();
  int lane = tid & 63;
  int wave = tid >> 6;
  int k = lane & 15, g = lane >> 4;
  int node = blockIdx.x * 16 + wave * 4 + g;
  float acc = 0.f;
  if (node < N) {
    const float4* hrow = reinterpret_cast<const float4*>(h + (size_t)node * 256);
#pragma unroll 8
    for (int c4 = 0; c4 < 64; ++c4) {
      float4 hv = hrow[c4];
      int cb = c4 * 4;
      acc += hv.x * Wps[(cb + 0) * 16 + k];
      acc += hv.y * Wps[(cb + 1) * 16 + k];
      acc += hv.z * Wps[(cb + 2) * 16 + k];
      acc += hv.w * Wps[(cb + 3) * 16 + k];
    }
    acc += bp[k];
  }
  float mx = acc;
#pragma unroll
  for (int off = 1; off < 16; off <<= 1) mx = fmaxf(mx, __shfl_xor(mx, off));
  float ex = (node < N) ? expf(acc - mx) : 0.f;
  float sm = ex;
#pragma unroll
  for (int off = 1; off < 16; off <<= 1) sm += __shfl_xor(sm, off);
  float sval = (node < N) ? ex / sm : 0.f;
  if (node < N) s_out[(size_t)node * 16 + k] = sval;
  float v = sval;
  v += __shfl_xor(v, 16);
  v += __shfl_xor(v, 32);
  if (lane < 16) atomicAdd(&cs_loc[lane], v);
  __syncthreads();
  if (tid < 16) cs_part[(size_t)blockIdx.x * 16 + tid] = cs_loc[tid];
}

// Per-edge partial reductions; LAST block reduces all partials and emits
// the 3 scalars (threadfence + device-scope atomic counter protocol).
__global__ __launch_bounds__(256) void edge_reduce(const int* __restrict__ ei,
                                                   const float* __restrict__ ew,
                                                   const float* __restrict__ s,
                                                   float* __restrict__ part,
                                                   const float* __restrict__ cs_part,
                                                   int pool_blocks,
                                                   int* __restrict__ ctr,
                                                   float* __restrict__ out,
                                                   int N, int s_elems, int E) {
  __shared__ float loc[18];
  int tid = threadIdx.x;
  if (tid < 18) loc[tid] = 0.f;
  __syncthreads();
  bool i64 = ei_is_i64(ei);
  float dot = 0.f, w = 0.f;
  float ca[16];
#pragma unroll
  for (int k = 0; k < 16; ++k) ca[k] = 0.f;
  for (int e = blockIdx.x * 256 + tid; e < E; e += gridDim.x * 256) {
    int a = ld_idx(ei, e, i64);
    int b = ld_idx(ei, E + e, i64);
    float we = ew[e];
    const float4* sa = reinterpret_cast<const float4*>(s + (size_t)a * 16);
    const float4* sb = reinterpret_cast<const float4*>(s + (size_t)b * 16);
    float d = 0.f;
#pragma unroll
    for (int q = 0; q < 4; ++q) {
      float4 av = sa[q], bv = sb[q];
      d += av.x * bv.x + av.y * bv.y + av.z * bv.z + av.w * bv.w;
      ca[q * 4 + 0] += we * av.x; ca[q * 4 + 1] += we * av.y;
      ca[q * 4 + 2] += we * av.z; ca[q * 4 + 3] += we * av.w;
    }
    dot += we * d;
    w += we;
  }
#pragma unroll
  for (int off = 32; off; off >>= 1) {
    dot += __shfl_xor(dot, off);
    w += __shfl_xor(w, off);
#pragma unroll
    for (int k = 0; k < 16; ++k) ca[k] += __shfl_xor(ca[k], off);
  }
  if ((tid & 63) == 0) {
    atomicAdd(&loc[0], dot);
    atomicAdd(&loc[1], w);
#pragma unroll
    for (int k = 0; k < 16; ++k) atomicAdd(&loc[2 + k], ca[k]);
  }
  __syncthreads();
  if (tid < 18) part[(size_t)blockIdx.x * 18 + tid] = loc[tid];

  // last-block finalize
  __shared__ bool amLast;
  __threadfence();
  if (tid == 0) amLast = (atomicAdd(ctr, 1) == (int)gridDim.x - 1);
  __syncthreads();
  if (!amLast) return;

  __shared__ float red[18];
  __shared__ float csl[256];
  __shared__ float cs[16];
  if (tid < 18) {
    float a = 0.f;
    for (int b = 0; b < (int)gridDim.x; ++b) a += part[(size_t)b * 18 + tid];
    red[tid] = a;
  }
  {
    int k = tid & 15, sl = tid >> 4;
    float a = 0.f;
    for (int b = sl; b < pool_blocks; b += 16) a += cs_part[(size_t)b * 16 + k];
    csl[tid] = a;
  }
  __syncthreads();
  if (tid < 16) {
    float a = 0.f;
#pragma unroll
    for (int sl = 0; sl < 16; ++sl) a += csl[sl * 16 + tid];
    cs[tid] = a;
  }
  __syncthreads();
  if (tid == 0) {
    float tr = red[0], m2 = red[1];
    float ca2 = 0.f, cs2 = 0.f;
    for (int k = 0; k < 16; ++k) {
      ca2 += red[2 + k] * red[2 + k];
      cs2 += cs[k] * cs[k];
    }
    float sp = -(tr - ca2 / m2) / m2;
    float cl = sqrtf(cs2) / (float)N * 4.0f - 1.0f;
    out[s_elems + 0] = 100.f * (sp + cl);
    out[s_elems + 1] = 100.f * sp;
    out[s_elems + 2] = 100.f * cl;
  }
}

extern "C" void kernel_launch(void* const* d_in, const int* in_sizes, int n_in,
                              void* d_out, int out_size, void* d_ws, size_t ws_size,
                              hipStream_t stream) {
  const float* x  = (const float*)d_in[0];
  const int*   ei = (const int*)d_in[1];
  const float* ew = (const float*)d_in[2];
  const float* W1 = (const float*)d_in[3];
  const float* b1 = (const float*)d_in[4];
  const float* W2 = (const float*)d_in[5];
  const float* b2 = (const float*)d_in[6];
  const float* Wp = (const float*)d_in[7];
  const float* bp = (const float*)d_in[8];
  float* out = (float*)d_out;

  const int IN_C = 128, HID = 256;
  const int N = in_sizes[0] / IN_C;   // 10000
  const int E = in_sizes[2];          // 160000
  const int pool_blocks = (N + 15) / 16;

  char* p = (char*)d_ws;
  auto alloc = [&](size_t b) { char* r = p; p += (b + 255) & ~(size_t)255; return r; };
  float* deg     = (float*)alloc((size_t)N * 4);
  int*   cnt     = (int*)alloc((size_t)N * 4);
  int*   cur     = (int*)alloc((size_t)N * 4);
  int*   ctr     = (int*)alloc(256);
  char*  zero_end = p;
  u16*   xbf     = (u16*)alloc((size_t)N * IN_C * 2);
  u16*   hbf     = (u16*)alloc((size_t)N * HID * 2);
  u16*   axhi    = (u16*)alloc((size_t)N * IN_C * 2);
  u16*   axlo    = (u16*)alloc((size_t)N * IN_C * 2);
  u16*   ahhi    = (u16*)alloc((size_t)N * HID * 2);
  u16*   ahlo    = (u16*)alloc((size_t)N * HID * 2);
  float* h2      = (float*)alloc((size_t)N * HID * 4);
  u16*   w1hi    = (u16*)alloc((size_t)256 * 128 * 2);
  u16*   w1lo    = (u16*)alloc((size_t)256 * 128 * 2);
  u16*   w2hi    = (u16*)alloc((size_t)256 * 256 * 2);
  u16*   w2lo    = (u16*)alloc((size_t)256 * 256 * 2);
  int*   rowptr  = (int*)alloc((size_t)(N + 1) * 4);
  int*   col     = (int*)alloc((size_t)E * 4);
  float* coef    = (float*)alloc((size_t)E * 4);
  float* epart   = (float*)alloc((size_t)ER_BLOCKS * 18 * 4);
  float* cs_part = (float*)alloc((size_t)pool_blocks * 16 * 4);
  if ((size_t)(p - (char*)d_ws) > ws_size) return;

  int zn4 = (int)((zero_end - (char*)deg) >> 4);
  int nx4 = (N * IN_C) / 4;
  int setup_items = zn4 + nx4 + 256 * 128 + 256 * 256;
  setup_kernel<<<(setup_items + 255) / 256, 256, 0, stream>>>(
      (int4*)deg, zn4, x, xbf, nx4, W1, w1hi, w1lo, W2, w2hi, w2lo);

  int eb = (E + 255) / 256;
  edge_count<<<eb, 256, 0, stream>>>(ei, ew, cnt, deg, E);
  scan_kernel<<<1, 1024, 0, stream>>>(cnt, rowptr, N);
  scatter_edges<<<eb, 256, 0, stream>>>(ei, ew, rowptr, cur, deg, col, coef, E);

  dim3 gg((N + 63) / 64, HID / 64);
  // layer 1
  aggregate_pre<128><<<N, 256, 0, stream>>>(xbf, rowptr, col, coef, deg, axhi, axlo, N);
  gemm_mfma<<<gg, 256, 0, stream>>>(axhi, axlo, w1hi, w1lo, b1, nullptr, hbf, N, IN_C, 1);
  // layer 2
  aggregate_pre<256><<<N, 256, 0, stream>>>(hbf, rowptr, col, coef, deg, ahhi, ahlo, N);
  gemm_mfma<<<gg, 256, 0, stream>>>(ahhi, ahlo, w2hi, w2lo, b2, h2, nullptr, N, HID, 0);

  pool_kernel<<<pool_blocks, 256, 0, stream>>>(h2, Wp, bp, out, cs_part, N);
  edge_reduce<<<ER_BLOCKS, 256, 0, stream>>>(ei, ew, out, epart, cs_part, pool_blocks,
                                             ctr, out, N, N * 16, E);
}

// Round 9
// 144.380 us; speedup vs baseline: 1.2070x; 1.2070x over previous
//
#include <hip/hip_runtime.h>
#include <math.h>

// ---------------------------------------------------------------------------
// DMoN pooling, edge-list formulation (dense adj never materialized).
//   0. setup: zero deg/wdeg/cnt/cur ; x->bf16 ; W1,W2 -> transposed bf16 hi/lo
//   1. CSR-by-dst build (count[+wdeg] / scan / scatter-with-inline-rsqrt)
//   2. layer 1: (axhi,axlo) = split(aggregate(x_bf)) ; h_bf = relu(ax@W1+b1)
//   3. layer 2: (ahhi,ahlo) = split(aggregate(h_bf)) ; h2 = relu(ah@W2+b2)
//   4. pool: s = softmax(h2@Wp+bp) -> d_out ; per-block partials of
//      cs[k]=SUM s[i][k], ca[k]=SUM wdeg[i]*s[i][k], wsum=SUM wdeg[i]
//   5. edge_reduce: ONLY tr = SUM_e w*dot(s[src],s[dst]) (4 lanes/edge)
//      NOTE: xor-4/8/16/32 reduce sums across GROUP bits only -> each group
//      counted once; no 0.25 scale (R8's bug: scaled an already-deduped sum).
//   6. finalize: parallel partial reduction, emit 3 scalars
// ---------------------------------------------------------------------------

#define ER_BLOCKS 512

typedef unsigned short u16;
typedef __attribute__((ext_vector_type(8))) short short8v;
typedef __attribute__((ext_vector_type(4))) float float4v;
typedef __attribute__((ext_vector_type(4))) unsigned short ushort4v;
typedef __attribute__((ext_vector_type(8))) unsigned short ushort8v;

__device__ __forceinline__ u16 f2bf_rne(float x) {
  unsigned u = __float_as_uint(x);
  u = (u + 0x7fffu + ((u >> 16) & 1u)) >> 16;
  return (u16)u;
}
__device__ __forceinline__ float bf2f(u16 h) {
  return __uint_as_float(((unsigned)h) << 16);
}

// edge_index declared int64 in the reference, but JAX without x64 keeps int32.
__device__ __forceinline__ bool ei_is_i64(const int* __restrict__ ei) {
  return ((ei[1] | ei[3] | ei[5] | ei[7]) == 0);
}
__device__ __forceinline__ int ld_idx(const int* __restrict__ ei, int pos, bool i64) {
  return i64 ? ei[2 * pos] : ei[pos];
}

// Fused setup: zero scratch region, x->bf16, W1/W2 -> [n][k] bf16 hi/lo.
__global__ __launch_bounds__(256) void setup_kernel(int4* __restrict__ zp, int zn4,
                                                    const float* __restrict__ x,
                                                    u16* __restrict__ xbf, int nx4,
                                                    const float* __restrict__ W1,
                                                    u16* __restrict__ w1hi, u16* __restrict__ w1lo,
                                                    const float* __restrict__ W2,
                                                    u16* __restrict__ w2hi, u16* __restrict__ w2lo) {
  const int T1 = 256 * 128, T2 = 256 * 256;
  int idx = blockIdx.x * 256 + threadIdx.x;
  if (idx < zn4) {
    zp[idx] = make_int4(0, 0, 0, 0);
    return;
  }
  idx -= zn4;
  if (idx < nx4) {
    float4 v = reinterpret_cast<const float4*>(x)[idx];
    ushort4v o = {f2bf_rne(v.x), f2bf_rne(v.y), f2bf_rne(v.z), f2bf_rne(v.w)};
    reinterpret_cast<ushort4v*>(xbf)[idx] = o;
    return;
  }
  idx -= nx4;
  if (idx < T1) {
    int n = idx >> 7, k = idx & 127;
    float v = W1[k * 256 + n];
    u16 h = f2bf_rne(v);
    w1hi[idx] = h;
    w1lo[idx] = f2bf_rne(v - bf2f(h));
    return;
  }
  idx -= T1;
  if (idx < T2) {
    int n = idx >> 8, k = idx & 255;
    float v = W2[k * 256 + n];
    u16 h = f2bf_rne(v);
    w2hi[idx] = h;
    w2lo[idx] = f2bf_rne(v - bf2f(h));
  }
}

// cnt/deg by dst (GCN norm), wdeg by src (DMoN degree vector).
__global__ __launch_bounds__(256) void edge_count(const int* __restrict__ ei,
                                                  const float* __restrict__ ew,
                                                  int* __restrict__ cnt,
                                                  float* __restrict__ deg,
                                                  float* __restrict__ wdeg, int E) {
  int e = blockIdx.x * 256 + threadIdx.x;
  if (e >= E) return;
  bool i64 = ei_is_i64(ei);
  int s = ld_idx(ei, e, i64);
  int d = ld_idx(ei, E + e, i64);
  float we = ew[e];
  atomicAdd(&cnt[d], 1);
  atomicAdd(&deg[d], we);
  atomicAdd(&wdeg[s], we);
}

__global__ __launch_bounds__(1024) void scan_kernel(const int* __restrict__ cnt,
                                                    int* __restrict__ rowptr, int n) {
  __shared__ int sums[1024];
  int tid = threadIdx.x;
  int CH = (n + 1023) >> 10;
  int beg = tid * CH, end = min(beg + CH, n);
  int s = 0;
  for (int i = beg; i < end; ++i) s += cnt[i];
  sums[tid] = s;
  __syncthreads();
  for (int off = 1; off < 1024; off <<= 1) {
    int v = (tid >= off) ? sums[tid - off] : 0;
    __syncthreads();
    sums[tid] += v;
    __syncthreads();
  }
  int run = (tid == 0) ? 0 : sums[tid - 1];
  for (int i = beg; i < end; ++i) { rowptr[i] = run; run += cnt[i]; }
  if (tid == 1023) rowptr[n] = run;
}

__global__ __launch_bounds__(256) void scatter_edges(const int* __restrict__ ei,
                                                     const float* __restrict__ ew,
                                                     const int* __restrict__ rowptr,
                                                     int* __restrict__ cur,
                                                     const float* __restrict__ deg,
                                                     int* __restrict__ col,
                                                     float* __restrict__ coef, int E) {
  int e = blockIdx.x * 256 + threadIdx.x;
  if (e >= E) return;
  bool i64 = ei_is_i64(ei);
  int s = ld_idx(ei, e, i64);
  int d = ld_idx(ei, E + e, i64);
  int p = rowptr[d] + atomicAdd(&cur[d], 1);
  col[p] = s;
  float ds = 1.0f / sqrtf(deg[s] + 1.0f);
  float dd = 1.0f / sqrtf(deg[d] + 1.0f);
  coef[p] = ds * ew[e] * dd;
}

// Normalized aggregation: bf16 gather (16B/lane), fp32 accum, hi/lo output.
template <int CH>
__global__ __launch_bounds__(256) void aggregate_pre(const u16* __restrict__ src,
                                                     const int* __restrict__ rowptr,
                                                     const int* __restrict__ col,
                                                     const float* __restrict__ coef,
                                                     const float* __restrict__ deg,
                                                     u16* __restrict__ ohi,
                                                     u16* __restrict__ olo, int N) {
  constexpr int Q = CH / 8;    // ushort8 lanes per row (16 or 32)
  constexpr int NS = 256 / Q;  // concurrent edge slots (16 or 8)
  int i = blockIdx.x;
  int t = threadIdx.x;
  int q = t % Q, slot = t / Q;
  int e0 = rowptr[i], e1 = rowptr[i + 1];
  float a[8] = {};
  for (int p = e0 + slot; p < e1; p += NS) {
    int c = col[p];
    float w = coef[p];
    ushort8v v = *reinterpret_cast<const ushort8v*>(&src[(size_t)c * CH + q * 8]);
#pragma unroll
    for (int j = 0; j < 8; ++j) a[j] += w * bf2f(v[j]);
  }
  __shared__ float red[256][9];  // +1 pad: spread banks
#pragma unroll
  for (int j = 0; j < 8; ++j) red[t][j] = a[j];
  __syncthreads();
  if (slot == 0) {
#pragma unroll
    for (int s2 = 1; s2 < NS; ++s2)
#pragma unroll
      for (int j = 0; j < 8; ++j) a[j] += red[s2 * Q + q][j];
    float w0 = 1.0f / (deg[i] + 1.0f);
    ushort8v xv = *reinterpret_cast<const ushort8v*>(&src[(size_t)i * CH + q * 8]);
    ushort8v hv, lv;
#pragma unroll
    for (int j = 0; j < 8; ++j) {
      a[j] += w0 * bf2f(xv[j]);
      u16 h = f2bf_rne(a[j]);
      hv[j] = h;
      lv[j] = f2bf_rne(a[j] - bf2f(h));
    }
    *reinterpret_cast<ushort8v*>(&ohi[(size_t)i * CH + q * 8]) = hv;
    *reinterpret_cast<ushort8v*>(&olo[(size_t)i * CH + q * 8]) = lv;
  }
}

// C[M,256] = relu(A@B + bias) via 3-term bf16 MFMA (A=Ahi+Alo, B=Bhi+Blo).
__global__ __launch_bounds__(256) void gemm_mfma(const u16* __restrict__ Ahi,
                                                 const u16* __restrict__ Alo,
                                                 const u16* __restrict__ Wthi,
                                                 const u16* __restrict__ Wtlo,
                                                 const float* __restrict__ bias,
                                                 float* __restrict__ C,
                                                 u16* __restrict__ Cbf,
                                                 int M, int K, int outbf) {
  __shared__ u16 As_hi[64][40], As_lo[64][40];
  __shared__ u16 Bs_hi[64][40], Bs_lo[64][40];
  int tid = threadIdx.x;
  int w = tid >> 6, l = tid & 63;
  int wm = w >> 1, wn = w & 1;
  int row0 = blockIdx.x * 64, col0 = blockIdx.y * 64;
  int srow = tid >> 2, sc = (tid & 3) * 8;
  int fr = l & 15, kg = (l >> 4) * 8;

  float4v acc[2][2];
#pragma unroll
  for (int i = 0; i < 2; ++i)
#pragma unroll
    for (int j = 0; j < 2; ++j) acc[i][j] = (float4v){0.f, 0.f, 0.f, 0.f};

  for (int k0 = 0; k0 < K; k0 += 32) {
    {
      int gr = row0 + srow;
      uint4 zero = make_uint4(0, 0, 0, 0);
      uint4 vh = zero, vl = zero;
      if (gr < M) {
        vh = *reinterpret_cast<const uint4*>(&Ahi[(size_t)gr * K + k0 + sc]);
        vl = *reinterpret_cast<const uint4*>(&Alo[(size_t)gr * K + k0 + sc]);
      }
      *reinterpret_cast<uint4*>(&As_hi[srow][sc]) = vh;
      *reinterpret_cast<uint4*>(&As_lo[srow][sc]) = vl;
      int bn = col0 + srow;
      uint4 bh = *reinterpret_cast<const uint4*>(&Wthi[(size_t)bn * K + k0 + sc]);
      uint4 bl = *reinterpret_cast<const uint4*>(&Wtlo[(size_t)bn * K + k0 + sc]);
      *reinterpret_cast<uint4*>(&Bs_hi[srow][sc]) = bh;
      *reinterpret_cast<uint4*>(&Bs_lo[srow][sc]) = bl;
    }
    __syncthreads();
    short8v ah[2], al[2], bh[2], bl[2];
#pragma unroll
    for (int i = 0; i < 2; ++i) {
      int r = wm * 32 + i * 16 + fr;
      ah[i] = *reinterpret_cast<const short8v*>(&As_hi[r][kg]);
      al[i] = *reinterpret_cast<const short8v*>(&As_lo[r][kg]);
    }
#pragma unroll
    for (int j = 0; j < 2; ++j) {
      int n = wn * 32 + j * 16 + fr;
      bh[j] = *reinterpret_cast<const short8v*>(&Bs_hi[n][kg]);
      bl[j] = *reinterpret_cast<const short8v*>(&Bs_lo[n][kg]);
    }
#pragma unroll
    for (int i = 0; i < 2; ++i)
#pragma unroll
      for (int j = 0; j < 2; ++j) {
        acc[i][j] = __builtin_amdgcn_mfma_f32_16x16x32_bf16(ah[i], bh[j], acc[i][j], 0, 0, 0);
        acc[i][j] = __builtin_amdgcn_mfma_f32_16x16x32_bf16(al[i], bh[j], acc[i][j], 0, 0, 0);
        acc[i][j] = __builtin_amdgcn_mfma_f32_16x16x32_bf16(ah[i], bl[j], acc[i][j], 0, 0, 0);
      }
    __syncthreads();
  }
#pragma unroll
  for (int j = 0; j < 2; ++j) {
    int gc = col0 + wn * 32 + j * 16 + fr;
    float bj = bias[gc];
#pragma unroll
    for (int i = 0; i < 2; ++i) {
#pragma unroll
      for (int r = 0; r < 4; ++r) {
        int gr = row0 + wm * 32 + i * 16 + (l >> 4) * 4 + r;
        if (gr < M) {
          float v = fmaxf(acc[i][j][r] + bj, 0.0f);
          if (outbf) Cbf[(size_t)gr * 256 + gc] = f2bf_rne(v);
          else       C[(size_t)gr * 256 + gc] = v;
        }
      }
    }
  }
}

// Pooling + softmax; per-block partials: [0..15]=cs, [16..31]=ca, [32]=wsum.
__global__ __launch_bounds__(256) void pool_kernel(const float* __restrict__ h,
                                                   const float* __restrict__ Wp,
                                                   const float* __restrict__ bp,
                                                   const float* __restrict__ wdeg,
                                                   float* __restrict__ s_out,
                                                   float* __restrict__ pp, int N) {
  __shared__ float Wps[256 * 16];
  __shared__ float loc[33];
  int tid = threadIdx.x;
  for (int idx = tid; idx < 4096; idx += 256) Wps[idx] = Wp[idx];
  if (tid < 33) loc[tid] = 0.f;
  __syncthreads();
  int lane = tid & 63;
  int wave = tid >> 6;
  int k = lane & 15, g = lane >> 4;
  int node = blockIdx.x * 16 + wave * 4 + g;
  float acc = 0.f, wd = 0.f;
  if (node < N) {
    wd = wdeg[node];
    const float4* hrow = reinterpret_cast<const float4*>(h + (size_t)node * 256);
#pragma unroll 8
    for (int c4 = 0; c4 < 64; ++c4) {
      float4 hv = hrow[c4];
      int cb = c4 * 4;
      acc += hv.x * Wps[(cb + 0) * 16 + k];
      acc += hv.y * Wps[(cb + 1) * 16 + k];
      acc += hv.z * Wps[(cb + 2) * 16 + k];
      acc += hv.w * Wps[(cb + 3) * 16 + k];
    }
    acc += bp[k];
  }
  float mx = acc;
#pragma unroll
  for (int off = 1; off < 16; off <<= 1) mx = fmaxf(mx, __shfl_xor(mx, off));
  float ex = (node < N) ? expf(acc - mx) : 0.f;
  float sm = ex;
#pragma unroll
  for (int off = 1; off < 16; off <<= 1) sm += __shfl_xor(sm, off);
  float sval = (node < N) ? ex / sm : 0.f;
  if (node < N) s_out[(size_t)node * 16 + k] = sval;
  float v = sval;            // cs
  float v2 = wd * sval;      // ca = s.T @ deg
  float v3 = (k == 0) ? wd : 0.f;  // wsum (each node once)
  v += __shfl_xor(v, 16);  v += __shfl_xor(v, 32);
  v2 += __shfl_xor(v2, 16); v2 += __shfl_xor(v2, 32);
  v3 += __shfl_xor(v3, 16); v3 += __shfl_xor(v3, 32);
  if (lane < 16) {
    atomicAdd(&loc[lane], v);
    atomicAdd(&loc[16 + lane], v2);
  }
  if (lane == 0) atomicAdd(&loc[32], v3);
  __syncthreads();
  if (tid < 33) pp[(size_t)blockIdx.x * 33 + tid] = loc[tid];
}

// tr = SUM_e w*dot(s[src],s[dst]); 4 lanes per edge; 1 float partial/block.
__global__ __launch_bounds__(256) void edge_reduce(const int* __restrict__ ei,
                                                   const float* __restrict__ ew,
                                                   const float* __restrict__ s,
                                                   float* __restrict__ part, int E) {
  int tid = threadIdx.x;
  bool i64 = ei_is_i64(ei);
  int le = tid >> 2, sub = tid & 3;
  int epi = gridDim.x * 64;  // edges per grid iteration
  float acc = 0.f;
  for (int e = blockIdx.x * 64 + le; e < E; e += epi) {
    int a = ld_idx(ei, e, i64);
    int b = ld_idx(ei, E + e, i64);
    float w = ew[e];
    float4 av = *reinterpret_cast<const float4*>(s + (size_t)a * 16 + sub * 4);
    float4 bv = *reinterpret_cast<const float4*>(s + (size_t)b * 16 + sub * 4);
    float d = av.x * bv.x + av.y * bv.y + av.z * bv.z + av.w * bv.w;
    d += __shfl_xor(d, 1);
    d += __shfl_xor(d, 2);
    acc += w * d;  // 4 lane-copies per group; xor-4+ reduce picks one copy
  }
#pragma unroll
  for (int off = 4; off < 64; off <<= 1) acc += __shfl_xor(acc, off);
  __shared__ float loc;
  if (tid == 0) loc = 0.f;
  __syncthreads();
  if ((tid & 63) == 0) atomicAdd(&loc, acc);
  __syncthreads();
  if (tid == 0) part[blockIdx.x] = loc;  // no 0.25: already single-counted
}

// Parallel finalize: reduce ER_BLOCKS trace-partials + pb x 33 pool partials.
__global__ __launch_bounds__(256) void finalize(const float* __restrict__ epart,
                                                const float* __restrict__ pp, int pb,
                                                float* __restrict__ out,
                                                int N, int s_elems) {
  __shared__ float cred[256];
  __shared__ float vals[32];
  __shared__ float scal[2];  // [0]=tr, [1]=wsum
  int tid = threadIdx.x;
  float a = 0.f;
  for (int b = tid; b < ER_BLOCKS; b += 256) a += epart[b];
  float wv = 0.f;
  for (int b = tid; b < pb; b += 256) wv += pp[(size_t)b * 33 + 32];
#pragma unroll
  for (int off = 1; off < 64; off <<= 1) {
    a += __shfl_xor(a, off);
    wv += __shfl_xor(wv, off);
  }
  if (tid == 0) { scal[0] = 0.f; scal[1] = 0.f; }
  __syncthreads();
  if ((tid & 63) == 0) {
    atomicAdd(&scal[0], a);
    atomicAdd(&scal[1], wv);
  }
  {
    int k = tid & 31, sl = tid >> 5;
    float c = 0.f;
    for (int b = sl; b < pb; b += 8) c += pp[(size_t)b * 33 + k];
    cred[tid] = c;
  }
  __syncthreads();
  if (tid < 32) {
    float c = cred[tid];
#pragma unroll
    for (int sl = 1; sl < 8; ++sl) c += cred[sl * 32 + tid];
    vals[tid] = c;
  }
  __syncthreads();
  if (tid == 0) {
    float tr = scal[0], m2 = scal[1];
    float ca2 = 0.f, cs2 = 0.f;
    for (int k = 0; k < 16; ++k) {
      cs2 += vals[k] * vals[k];
      ca2 += vals[16 + k] * vals[16 + k];
    }
    float sp = -(tr - ca2 / m2) / m2;
    float cl = sqrtf(cs2) / (float)N * 4.0f - 1.0f;
    out[s_elems + 0] = 100.f * (sp + cl);
    out[s_elems + 1] = 100.f * sp;
    out[s_elems + 2] = 100.f * cl;
  }
}

extern "C" void kernel_launch(void* const* d_in, const int* in_sizes, int n_in,
                              void* d_out, int out_size, void* d_ws, size_t ws_size,
                              hipStream_t stream) {
  const float* x  = (const float*)d_in[0];
  const int*   ei = (const int*)d_in[1];
  const float* ew = (const float*)d_in[2];
  const float* W1 = (const float*)d_in[3];
  const float* b1 = (const float*)d_in[4];
  const float* W2 = (const float*)d_in[5];
  const float* b2 = (const float*)d_in[6];
  const float* Wp = (const float*)d_in[7];
  const float* bp = (const float*)d_in[8];
  float* out = (float*)d_out;

  const int IN_C = 128, HID = 256;
  const int N = in_sizes[0] / IN_C;   // 10000
  const int E = in_sizes[2];          // 160000
  const int pool_blocks = (N + 15) / 16;

  char* p = (char*)d_ws;
  auto alloc = [&](size_t b) { char* r = p; p += (b + 255) & ~(size_t)255; return r; };
  float* deg     = (float*)alloc((size_t)N * 4);
  float* wdeg    = (float*)alloc((size_t)N * 4);
  int*   cnt     = (int*)alloc((size_t)N * 4);
  int*   cur     = (int*)alloc((size_t)N * 4);
  char*  zero_end = p;
  u16*   xbf     = (u16*)alloc((size_t)N * IN_C * 2);
  u16*   hbf     = (u16*)alloc((size_t)N * HID * 2);
  u16*   axhi    = (u16*)alloc((size_t)N * IN_C * 2);
  u16*   axlo    = (u16*)alloc((size_t)N * IN_C * 2);
  u16*   ahhi    = (u16*)alloc((size_t)N * HID * 2);
  u16*   ahlo    = (u16*)alloc((size_t)N * HID * 2);
  float* h2      = (float*)alloc((size_t)N * HID * 4);
  u16*   w1hi    = (u16*)alloc((size_t)256 * 128 * 2);
  u16*   w1lo    = (u16*)alloc((size_t)256 * 128 * 2);
  u16*   w2hi    = (u16*)alloc((size_t)256 * 256 * 2);
  u16*   w2lo    = (u16*)alloc((size_t)256 * 256 * 2);
  int*   rowptr  = (int*)alloc((size_t)(N + 1) * 4);
  int*   col     = (int*)alloc((size_t)E * 4);
  float* coef    = (float*)alloc((size_t)E * 4);
  float* epart   = (float*)alloc((size_t)ER_BLOCKS * 4);
  float* pp      = (float*)alloc((size_t)pool_blocks * 33 * 4);
  if ((size_t)(p - (char*)d_ws) > ws_size) return;

  int zn4 = (int)((zero_end - (char*)deg) >> 4);
  int nx4 = (N * IN_C) / 4;
  int setup_items = zn4 + nx4 + 256 * 128 + 256 * 256;
  setup_kernel<<<(setup_items + 255) / 256, 256, 0, stream>>>(
      (int4*)deg, zn4, x, xbf, nx4, W1, w1hi, w1lo, W2, w2hi, w2lo);

  int eb = (E + 255) / 256;
  edge_count<<<eb, 256, 0, stream>>>(ei, ew, cnt, deg, wdeg, E);
  scan_kernel<<<1, 1024, 0, stream>>>(cnt, rowptr, N);
  scatter_edges<<<eb, 256, 0, stream>>>(ei, ew, rowptr, cur, deg, col, coef, E);

  dim3 gg((N + 63) / 64, HID / 64);
  aggregate_pre<128><<<N, 256, 0, stream>>>(xbf, rowptr, col, coef, deg, axhi, axlo, N);
  gemm_mfma<<<gg, 256, 0, stream>>>(axhi, axlo, w1hi, w1lo, b1, nullptr, hbf, N, IN_C, 1);
  aggregate_pre<256><<<N, 256, 0, stream>>>(hbf, rowptr, col, coef, deg, ahhi, ahlo, N);
  gemm_mfma<<<gg, 256, 0, stream>>>(ahhi, ahlo, w2hi, w2lo, b2, h2, nullptr, N, HID, 0);

  pool_kernel<<<pool_blocks, 256, 0, stream>>>(h2, Wp, bp, wdeg, out, pp, N);
  edge_reduce<<<ER_BLOCKS, 256, 0, stream>>>(ei, ew, out, epart, E);
  finalize<<<1, 256, 0, stream>>>(epart, pp, pool_blocks, out, N, N * 16);
}